// Round 10
// baseline (183.696 us; speedup 1.0000x reference)
//
#include <hip/hip_runtime.h>
#include <cstdint>
#include <cstddef>

// Linear attention: B=4 N=4096 C=768 H=12 d=64
// Pipeline: fused cast->bf16, GEMM1 256x256 8-phase kk-split (x@Wqkv^T, phi),
// kv/ksum partials, reduce (kv->bf16), y via MFMA, GEMM2 128x128 BK=64.

typedef __attribute__((ext_vector_type(8))) short bf16x8;
typedef __attribute__((ext_vector_type(4))) float f32x4;

__device__ __forceinline__ unsigned short f2bf(float f) {
  uint32_t u = __builtin_bit_cast(uint32_t, f);
  u += 0x7FFFu + ((u >> 16) & 1u);  // RNE
  return (unsigned short)(u >> 16);
}
__device__ __forceinline__ float bf2f(unsigned short h) {
  uint32_t u = ((uint32_t)h) << 16;
  return __builtin_bit_cast(float, u);
}

__global__ __launch_bounds__(256) void cast3_kernel(
    const float* __restrict__ a, const float* __restrict__ b,
    const float* __restrict__ c, unsigned short* __restrict__ oa,
    unsigned short* __restrict__ ob, unsigned short* __restrict__ oc,
    int na4, int nb4, int nc4) {
  int i = blockIdx.x * 256 + threadIdx.x;
  const float* src;
  unsigned short* dst;
  if (i < na4) {
    src = a; dst = oa;
  } else if (i < na4 + nb4) {
    i -= na4; src = b; dst = ob;
  } else if (i < na4 + nb4 + nc4) {
    i -= na4 + nb4; src = c; dst = oc;
  } else {
    return;
  }
  float4 v = reinterpret_cast<const float4*>(src)[i];
  ushort4 o;
  o.x = f2bf(v.x); o.y = f2bf(v.y); o.z = f2bf(v.z); o.w = f2bf(v.w);
  reinterpret_cast<ushort4*>(dst)[i] = o;
}

#define GLOAD_LDS16(g, s)                                                     \
  __builtin_amdgcn_global_load_lds(                                           \
      (const __attribute__((address_space(1))) void*)(g),                     \
      (__attribute__((address_space(3))) void*)(s), 16, 0, 0)

__device__ __forceinline__ int xcd_swizzle(int lin, int nwg) {
  const int q = nwg >> 3, r = nwg & 7;
  const int xcd = lin & 7, idx = lin >> 3;
  return (xcd < r ? xcd * (q + 1) : r * (q + 1) + (xcd - r) * q) + idx;
}

// ============================================================================
// 256x256 tile, BK=64, 8 waves (2M x 4N), 512 thr, LDS 128KB = 2buf x
// 2 K-halves x 256x32 x {A,B}.  Key derivation: splitting LDS halves by K
// (kk0/kk1 COLUMNS) gives frees {A.h0:end-P1, B.h0:end-P2, A.h1:end-P3,
// B.h1:end-P4} so a 1-half-per-phase stage schedule exists with vmcnt(6)
// only at P4/P8 (counted: 8 issued since last vmcnt, wait leaves 6 = the 3
// newest halves in flight).  Verified edges:
//   stage P1:B[t+1].h1  P2:A[t+2].h0  P3:B[t+2].h0  P4:A[t+2].h1+vm6
//         P5:B[t+2].h1  P6:A[t+3].h0  P7:B[t+3].h0  P8:A[t+3].h1+vm6
//   vm6@P4 guarantees <=P1 landed (tile t+1 complete, read P5-P8)
//   vm6@P8 guarantees <=P5 landed (tile t+2 complete, read next P1-P4)
// Phase: {ds_read(10 or 2), stage(2 gload), bar, setprio1, 16 MFMA,
// setprio0, [vm], bar, fence}.  No sched_barrier, no asm lgkmcnt (reads are
// compiler-visible).  XOR chunk swizzle both-sides (rule #21), 2-way banks.
// ============================================================================
#define VM6 asm volatile("s_waitcnt vmcnt(6)" ::: "memory")
#define VM0 asm volatile("s_waitcnt vmcnt(0)" ::: "memory")
#define FENCE asm volatile("" ::: "memory")

template <int PHI_COLS, bool OUT_BF16, bool BIAS>
__global__ __launch_bounds__(512, 2) void gemm256_kk(
    const unsigned short* __restrict__ A, const unsigned short* __restrict__ B,
    void* __restrict__ Cout, const float* __restrict__ bias, int M, int N, int K) {
  __shared__ unsigned short sm[65536];  // A:[0,32768) B:[32768,65536) ushorts
  const int t = threadIdx.x;
  const int w = t >> 6;
  const int l = t & 63;
  const int r16 = l & 15;
  const int c4 = l >> 4;

  const int nx = gridDim.x;
  const int lin = xcd_swizzle(blockIdx.y * nx + blockIdx.x, gridDim.x * gridDim.y);
  const int m0 = (lin / nx) * 256;
  const int n0 = (lin % nx) * 256;

  // staging: thread t -> row t>>2 (0..127; +128 on 2nd load), chunk t&3 of a
  // 32-col K-half; source chunk pre-swizzled by (row>>1)&3.
  const int srow = t >> 2;
  const int sck = (t & 3) ^ ((t >> 3) & 3);
  const unsigned short* gA = A + (size_t)(m0 + srow) * K + sck * 8;
  const unsigned short* gB = B + (size_t)(n0 + srow) * K + sck * 8;
  const int lds_st = w * 512;  // wave-uniform dest (HW adds lane*16B)

#define STG(gp_, lo_, T_, kh_)                                                \
  {                                                                           \
    const int d_ = (lo_) + ((T_) & 1) * 16384 + (kh_) * 8192 + lds_st;        \
    const size_t g_ = (size_t)(T_) * 64 + (kh_) * 32;                         \
    GLOAD_LDS16(gp_ + g_, &sm[d_]);                                           \
    GLOAD_LDS16(gp_ + g_ + (size_t)128 * K, &sm[d_ + 4096]);                  \
  }
#define SA0(T_) STG(gA, 0, T_, 0)
#define SA1(T_) STG(gA, 0, T_, 1)
#define SB0(T_) STG(gB, 32768, T_, 0)
#define SB1(T_) STG(gB, 32768, T_, 1)
#define SNONE

  // fragment read offsets: row*32 + swizzled chunk (2-way banks = free)
  const int wm = (w >> 2) * 128;
  const int wn = (w & 3) * 64;
  const int rsw = (c4 ^ ((r16 >> 1) & 3)) * 8;
  const int arow = (wm + r16) * 32 + rsw;  // + mi*512 + kk*8192 + buf*16384
  const int brow = (wn + r16) * 32 + rsw;  // + ni*512 + ... + 32768

  f32x4 acc[8][4] = {};

#define MM(mi_, ni_, a_, b_)                                                  \
  acc[mi_][ni_] = __builtin_amdgcn_mfma_f32_16x16x32_bf16(a_, b_, acc[mi_][ni_], 0, 0, 0)

#define TILE_PHASES(T_, S1_, S2_, S3_, S4_, VM4_)                             \
  {                                                                           \
    const int ba_ = ((T_) & 1) * 16384;                                       \
    const int bb_ = 32768 + ba_;                                              \
    bf16x8 a[8], p, q;                                                        \
    /* ---- P1: A kk0 (8) + B n0-1 kk0 (2); MFMA n0-1 kk0 ---- */             \
    _Pragma("unroll") for (int mi = 0; mi < 8; ++mi)                          \
        a[mi] = *reinterpret_cast<const bf16x8*>(&sm[ba_ + arow + mi * 512]); \
    p = *reinterpret_cast<const bf16x8*>(&sm[bb_ + brow]);                    \
    q = *reinterpret_cast<const bf16x8*>(&sm[bb_ + brow + 512]);              \
    S1_;                                                                      \
    __builtin_amdgcn_s_barrier();                                             \
    __builtin_amdgcn_s_setprio(1);                                            \
    _Pragma("unroll") for (int mi = 0; mi < 8; ++mi) {                        \
      MM(mi, 0, a[mi], p);                                                    \
      MM(mi, 1, a[mi], q);                                                    \
    }                                                                         \
    __builtin_amdgcn_s_setprio(0);                                            \
    __builtin_amdgcn_s_barrier();                                             \
    FENCE;                                                                    \
    /* ---- P2: B n2-3 kk0 (2); MFMA n2-3 kk0 ---- */                         \
    p = *reinterpret_cast<const bf16x8*>(&sm[bb_ + brow + 1024]);             \
    q = *reinterpret_cast<const bf16x8*>(&sm[bb_ + brow + 1536]);             \
    S2_;                                                                      \
    __builtin_amdgcn_s_barrier();                                             \
    __builtin_amdgcn_s_setprio(1);                                            \
    _Pragma("unroll") for (int mi = 0; mi < 8; ++mi) {                        \
      MM(mi, 2, a[mi], p);                                                    \
      MM(mi, 3, a[mi], q);                                                    \
    }                                                                         \
    __builtin_amdgcn_s_setprio(0);                                            \
    __builtin_amdgcn_s_barrier();                                             \
    FENCE;                                                                    \
    /* ---- P3: A kk1 (8) + B n0-1 kk1 (2); MFMA n0-1 kk1 ---- */             \
    _Pragma("unroll") for (int mi = 0; mi < 8; ++mi)                          \
        a[mi] = *reinterpret_cast<const bf16x8*>(                             \
            &sm[ba_ + 8192 + arow + mi * 512]);                               \
    p = *reinterpret_cast<const bf16x8*>(&sm[bb_ + 8192 + brow]);             \
    q = *reinterpret_cast<const bf16x8*>(&sm[bb_ + 8192 + brow + 512]);       \
    S3_;                                                                      \
    __builtin_amdgcn_s_barrier();                                             \
    __builtin_amdgcn_s_setprio(1);                                            \
    _Pragma("unroll") for (int mi = 0; mi < 8; ++mi) {                        \
      MM(mi, 0, a[mi], p);                                                    \
      MM(mi, 1, a[mi], q);                                                    \
    }                                                                         \
    __builtin_amdgcn_s_setprio(0);                                            \
    __builtin_amdgcn_s_barrier();                                             \
    FENCE;                                                                    \
    /* ---- P4: B n2-3 kk1 (2); MFMA n2-3 kk1; vmcnt; bar ---- */             \
    p = *reinterpret_cast<const bf16x8*>(&sm[bb_ + 8192 + brow + 1024]);      \
    q = *reinterpret_cast<const bf16x8*>(&sm[bb_ + 8192 + brow + 1536]);      \
    S4_;                                                                      \
    __builtin_amdgcn_s_barrier();                                             \
    __builtin_amdgcn_s_setprio(1);                                            \
    _Pragma("unroll") for (int mi = 0; mi < 8; ++mi) {                        \
      MM(mi, 2, a[mi], p);                                                    \
      MM(mi, 3, a[mi], q);                                                    \
    }                                                                         \
    __builtin_amdgcn_s_setprio(0);                                            \
    VM4_;                                                                     \
    __builtin_amdgcn_s_barrier();                                             \
    FENCE;                                                                    \
  }

  const int NT = K >> 6;  // 64-K tiles; 12 for K=768 (even, >=4)

  // prologue: tile 0 fully (8 loads) then tile 1 minus B.h1 (6 loads);
  // vmcnt(6) -> tile 0 landed, tile 1's 6 loads may fly.
  SA0(0) SA1(0) SB0(0) SB1(0)
  SA0(1) SB0(1) SA1(1)
  VM6;
  __builtin_amdgcn_s_barrier();
  FENCE;

  for (int tt = 0; tt + 2 < NT; tt += 2) {
    TILE_PHASES(tt,     SB1(tt + 1), SA0(tt + 2), SB0(tt + 2), SA1(tt + 2), VM6);
    TILE_PHASES(tt + 1, SB1(tt + 2), SA0(tt + 3), SB0(tt + 3), SA1(tt + 3), VM6);
  }
  // peeled final pair: only B[NT-1].h1 left to stage; drain at P4.
  TILE_PHASES(NT - 2, SB1(NT - 1), SNONE, SNONE, SNONE, VM0);
  TILE_PHASES(NT - 1, SNONE, SNONE, SNONE, SNONE, SNONE);

  // epilogue: C/D layout col=lane&15, row=(lane>>4)*4+reg (m89/m91 verified)
#pragma unroll
  for (int mi = 0; mi < 8; ++mi) {
    const int row0 = m0 + wm + mi * 16 + c4 * 4;
#pragma unroll
    for (int ni = 0; ni < 4; ++ni) {
      const int col = n0 + wn + ni * 16 + r16;
      float bv = 0.0f;
      if constexpr (BIAS) bv = bias[col];
      f32x4 v = acc[mi][ni];
#pragma unroll
      for (int r = 0; r < 4; ++r) {
        float x = v[r] + bv;
        if constexpr (PHI_COLS > 0) {
          if (col < PHI_COLS) x = (x > 0.0f) ? (x + 1.0f) : __expf(x);  // elu+1
        }
        if constexpr (OUT_BF16)
          ((unsigned short*)Cout)[(size_t)(row0 + r) * N + col] = f2bf(x);
        else
          ((float*)Cout)[(size_t)(row0 + r) * N + col] = x;
      }
    }
  }
#undef STG
#undef SA0
#undef SA1
#undef SB0
#undef SB1
#undef SNONE
#undef MM
#undef TILE_PHASES
}

// ============================================================================
// PROVEN 128x128 BK=64 m97-style kernel (round 6/9: GEMM2 and fallback).
// ============================================================================
template <int PHI_COLS, bool OUT_BF16, bool BIAS>
__global__ __launch_bounds__(256) void gemm128(
    const unsigned short* __restrict__ A, const unsigned short* __restrict__ B,
    void* __restrict__ Cout, const float* __restrict__ bias, int M, int N, int K) {
  __shared__ unsigned short As[128 * 64];
  __shared__ unsigned short Bs[128 * 64];
  const int t = threadIdx.x;
  const int w = t >> 6;
  const int l = t & 63;
  const int r16 = l & 15;
  const int c4 = l >> 4;

  const int nx = gridDim.x;
  const int lin = xcd_swizzle(blockIdx.y * nx + blockIdx.x, gridDim.x * gridDim.y);
  const int m0 = (lin / nx) * 128;
  const int n0 = (lin % nx) * 128;

  const int srow = t >> 3;
  const int schunk = (t & 7) ^ ((t >> 3) & 7);
  const unsigned short* gA = A + (size_t)(m0 + srow) * K + schunk * 8;
  const unsigned short* gB = B + (size_t)(n0 + srow) * K + schunk * 8;
  const int lbase = w * 512;

  const int wm = (w >> 1) * 64;
  const int wn = (w & 1) * 64;

  f32x4 acc[4][4] = {};

  for (int k0 = 0; k0 < K; k0 += 64) {
#pragma unroll
    for (int i = 0; i < 4; ++i) {
      GLOAD_LDS16(gA + k0 + (size_t)i * 32 * K, &As[lbase + i * 2048]);
      GLOAD_LDS16(gB + k0 + (size_t)i * 32 * K, &Bs[lbase + i * 2048]);
    }
    __syncthreads();
#pragma unroll
    for (int kk = 0; kk < 2; ++kk) {
      bf16x8 af[4], bfr[4];
#pragma unroll
      for (int mi = 0; mi < 4; ++mi) {
        const int R = wm + mi * 16 + r16;
        const int ch = (kk * 4 + c4) ^ (R & 7);
        af[mi] = *reinterpret_cast<const bf16x8*>(&As[R * 64 + ch * 8]);
      }
#pragma unroll
      for (int ni = 0; ni < 4; ++ni) {
        const int R = wn + ni * 16 + r16;
        const int ch = (kk * 4 + c4) ^ (R & 7);
        bfr[ni] = *reinterpret_cast<const bf16x8*>(&Bs[R * 64 + ch * 8]);
      }
#pragma unroll
      for (int mi = 0; mi < 4; ++mi)
#pragma unroll
        for (int ni = 0; ni < 4; ++ni)
          acc[mi][ni] = __builtin_amdgcn_mfma_f32_16x16x32_bf16(af[mi], bfr[ni], acc[mi][ni], 0, 0, 0);
    }
    __syncthreads();
  }

  const int rbase = c4 * 4;
#pragma unroll
  for (int mi = 0; mi < 4; ++mi) {
    const int row = m0 + wm + mi * 16 + rbase;
#pragma unroll
    for (int ni = 0; ni < 4; ++ni) {
      const int col = n0 + wn + ni * 16 + r16;
      float bv = 0.0f;
      if constexpr (BIAS) bv = bias[col];
      f32x4 v = acc[mi][ni];
#pragma unroll
      for (int r = 0; r < 4; ++r) {
        float x = v[r] + bv;
        if constexpr (PHI_COLS > 0) {
          if (col < PHI_COLS) x = (x > 0.0f) ? (x + 1.0f) : __expf(x);
        }
        if constexpr (OUT_BF16)
          ((unsigned short*)Cout)[(size_t)(row + r) * N + col] = f2bf(x);
        else
          ((float*)Cout)[(size_t)(row + r) * N + col] = x;
      }
    }
  }
}

// kv[m,d] partials over 128-n chunks, 32 chunks per (b,h).
__global__ __launch_bounds__(256) void kv_partial_kernel(
    const unsigned short* __restrict__ qkv, float* __restrict__ kv_part,
    float* __restrict__ ksum_part) {
  const int bh = blockIdx.x;
  const int chunk = blockIdx.y;
  const int b = bh / 12, h = bh % 12;
  const int t = threadIdx.x;
  const int tm = (t >> 4) * 4;
  const int td = (t & 15) * 4;
  const unsigned short* base = qkv + ((size_t)(b * 4096 + chunk * 128)) * 2304;
  const unsigned short* kptr = base + 768 + h * 64 + td;
  const unsigned short* vptr = base + 1536 + h * 64 + tm;
  float acc[4][4] = {};
  float ks[4] = {};
#pragma unroll 8
  for (int n = 0; n < 128; ++n) {
    const size_t off = (size_t)n * 2304;
    ushort4 ku = *reinterpret_cast<const ushort4*>(kptr + off);
    ushort4 vu = *reinterpret_cast<const ushort4*>(vptr + off);
    float kf[4] = {bf2f(ku.x), bf2f(ku.y), bf2f(ku.z), bf2f(ku.w)};
    float vf[4] = {bf2f(vu.x), bf2f(vu.y), bf2f(vu.z), bf2f(vu.w)};
#pragma unroll
    for (int i = 0; i < 4; ++i)
#pragma unroll
      for (int j = 0; j < 4; ++j) acc[i][j] += vf[i] * kf[j];
#pragma unroll
    for (int j = 0; j < 4; ++j) ks[j] += kf[j];
  }
  float* kvp = kv_part + ((size_t)(bh * 32 + chunk)) * 4096;
#pragma unroll
  for (int i = 0; i < 4; ++i)
#pragma unroll
    for (int j = 0; j < 4; ++j) kvp[(tm + i) * 64 + td + j] = acc[i][j];
  if (tm == 0) {
    float* ksp = ksum_part + (size_t)(bh * 32 + chunk) * 64;
#pragma unroll
    for (int j = 0; j < 4; ++j) ksp[td + j] = ks[j];
  }
}

__global__ __launch_bounds__(256) void kv_reduce_kernel(
    const float* __restrict__ kv_part, const float* __restrict__ ksum_part,
    unsigned short* __restrict__ kvb, float* __restrict__ ksum) {
  const int bh = blockIdx.x;
  const int seg = blockIdx.y;
  const int t = threadIdx.x;
  const int e = seg * 1024 + t * 4;
  float4 s = {0.f, 0.f, 0.f, 0.f};
#pragma unroll
  for (int c = 0; c < 32; ++c) {
    float4 v = *reinterpret_cast<const float4*>(
        &kv_part[((size_t)(bh * 32 + c)) * 4096 + e]);
    s.x += v.x; s.y += v.y; s.z += v.z; s.w += v.w;
  }
  ushort4 o;
  o.x = f2bf(s.x); o.y = f2bf(s.y); o.z = f2bf(s.z); o.w = f2bf(s.w);
  *reinterpret_cast<ushort4*>(&kvb[(size_t)bh * 4096 + e]) = o;
  if (seg == 0 && t < 64) {
    float ss = 0.f;
#pragma unroll
    for (int c = 0; c < 32; ++c) ss += ksum_part[(size_t)(bh * 32 + c) * 64 + t];
    ksum[bh * 64 + t] = ss;
  }
}

// y[n,m] = z[n] * sum_d q[n,d] kv[m,d], z[n]=1/(q[n,:].ksum+eps), via MFMA.
__global__ __launch_bounds__(256) void y_mfma_kernel(
    const unsigned short* __restrict__ qkv, const unsigned short* __restrict__ kvb,
    const float* __restrict__ ksum, unsigned short* __restrict__ ybf) {
  __shared__ unsigned short Qs[128 * 64];
  __shared__ unsigned short KVs[64 * 64];
  __shared__ float zs[128];
  const int bh = blockIdx.x;
  const int n0 = blockIdx.y * 128;
  const int b = bh / 12, h = bh % 12;
  const int t = threadIdx.x;
  const int w = t >> 6;
  const int l = t & 63;
  const int r16 = l & 15;
  const int c4 = l >> 4;

  const int srow = t >> 3;
  const int schunk = (t & 7) ^ ((t >> 3) & 7);
  const unsigned short* gQ =
      qkv + ((size_t)(b * 4096 + n0 + srow)) * 2304 + h * 64 + schunk * 8;
  const unsigned short* gKV = kvb + (size_t)bh * 4096 + srow * 64 + schunk * 8;
  const int lbase = w * 512;
#pragma unroll
  for (int i = 0; i < 4; ++i)
    GLOAD_LDS16(gQ + (size_t)i * 32 * 2304, &Qs[lbase + i * 2048]);
#pragma unroll
  for (int i = 0; i < 2; ++i)
    GLOAD_LDS16(gKV + i * 32 * 64, &KVs[lbase + i * 2048]);
  __syncthreads();

  const int wr = w * 32;
  f32x4 acc[2][4] = {};
#pragma unroll
  for (int kk = 0; kk < 2; ++kk) {
    bf16x8 af[2], bfr[4];
#pragma unroll
    for (int mi = 0; mi < 2; ++mi) {
      const int R = wr + mi * 16 + r16;
      const int ch = (kk * 4 + c4) ^ (R & 7);
      af[mi] = *reinterpret_cast<const bf16x8*>(&Qs[R * 64 + ch * 8]);
    }
#pragma unroll
    for (int ni = 0; ni < 4; ++ni) {
      const int R = ni * 16 + r16;
      const int ch = (kk * 4 + c4) ^ (R & 7);
      bfr[ni] = *reinterpret_cast<const bf16x8*>(&KVs[R * 64 + ch * 8]);
    }
#pragma unroll
    for (int mi = 0; mi < 2; ++mi)
#pragma unroll
      for (int ni = 0; ni < 4; ++ni)
        acc[mi][ni] = __builtin_amdgcn_mfma_f32_16x16x32_bf16(af[mi], bfr[ni], acc[mi][ni], 0, 0, 0);
  }

  if (t < 128) {
    const float* ks = ksum + bh * 64;
    float s = 0.f;
#pragma unroll
    for (int c = 0; c < 8; ++c) {
      bf16x8 qv = *reinterpret_cast<const bf16x8*>(&Qs[t * 64 + ((c ^ (t & 7)) * 8)]);
#pragma unroll
      for (int j = 0; j < 8; ++j) s += bf2f((unsigned short)qv[j]) * ks[c * 8 + j];
    }
    zs[t] = 1.0f / (s + 1e-6f);
  }
  __syncthreads();

  unsigned short* ybase = ybf + ((size_t)(b * 4096 + n0)) * 768 + h * 64;
#pragma unroll
  for (int mi = 0; mi < 2; ++mi) {
#pragma unroll
    for (int ni = 0; ni < 4; ++ni) {
      const int col = ni * 16 + r16;
      f32x4 v = acc[mi][ni];
#pragma unroll
      for (int r = 0; r < 4; ++r) {
        const int row = wr + mi * 16 + c4 * 4 + r;
        ybase[(size_t)row * 768 + col] = f2bf(v[r] * zs[row]);
      }
    }
  }
}

extern "C" void kernel_launch(void* const* d_in, const int* in_sizes, int n_in,
                              void* d_out, int out_size, void* d_ws, size_t ws_size,
                              hipStream_t stream) {
  const float* x = (const float*)d_in[0];
  const float* Wqkv = (const float*)d_in[1];
  const float* Wproj = (const float*)d_in[2];
  const float* bproj = (const float*)d_in[3];
  float* out = (float*)d_out;

  const int M = 16384;
  const int C = 768;
  const int N1 = 2304;

  char* ws = (char*)d_ws;
  size_t off = 0;
  unsigned short* xb = (unsigned short*)(ws + off);  off += (size_t)M * C * 2;
  unsigned short* wqb = (unsigned short*)(ws + off); off += (size_t)N1 * C * 2;
  unsigned short* wpb = (unsigned short*)(ws + off); off += (size_t)C * C * 2;
  unsigned short* qkvb = (unsigned short*)(ws + off); off += (size_t)M * N1 * 2;
  unsigned short* kvb = (unsigned short*)(ws + off); off += (size_t)48 * 4096 * 2;
  float* ksum = (float*)(ws + off);      off += (size_t)48 * 64 * 4;
  unsigned short* yb = (unsigned short*)(ws + off); off += (size_t)M * C * 2;
  float* ksum_part = (float*)(ws + off); off += (size_t)48 * 32 * 64 * 4;
  float* kv_part = (float*)xb;  // overlays xb (dead after GEMM1)

  const int na4 = M * C / 4, nb4 = N1 * C / 4, nc4 = C * C / 4;
  cast3_kernel<<<(na4 + nb4 + nc4 + 255) / 256, 256, 0, stream>>>(
      x, Wqkv, Wproj, xb, wqb, wpb, na4, nb4, nc4);

  // qkv = x @ Wqkv^T, phi fused on q,k columns, bf16 out — 8-phase 256^2
  gemm256_kk<1536, true, false>
      <<<dim3(N1 / 256, M / 256), 512, 0, stream>>>(xb, wqb, qkvb, nullptr, M, N1, C);

  kv_partial_kernel<<<dim3(48, 32), 256, 0, stream>>>(qkvb, kv_part, ksum_part);
  kv_reduce_kernel<<<dim3(48, 4), 256, 0, stream>>>(kv_part, ksum_part, kvb, ksum);
  y_mfma_kernel<<<dim3(48, 32), 256, 0, stream>>>(qkvb, kvb, ksum, yb);

  // out = y @ Wproj^T + b, fp32 out — proven 128^2 kernel
  gemm128<0, false, true>
      <<<dim3(C / 128, M / 128), 256, 0, stream>>>(yb, wpb, out, bproj, M, C, C);
}